// Round 2
// baseline (854.635 us; speedup 1.0000x reference)
//
#include <hip/hip_runtime.h>
#include <stdint.h>

typedef __bf16 bf16x8 __attribute__((ext_vector_type(8)));
typedef __bf16 bf16x4 __attribute__((ext_vector_type(4)));
typedef float f32x4 __attribute__((ext_vector_type(4)));

#define BM 128
#define BN 128
#define BK 64

// ---------------------------------------------------------------------------
// f32 -> bf16 conversion (weights). 8 elements/thread.
// ---------------------------------------------------------------------------
__global__ void cvt_bf16(const float* __restrict__ in, __bf16* __restrict__ out,
                         long n) {
    long idx = ((long)blockIdx.x * blockDim.x + threadIdx.x) * 8;
    if (idx >= n) return;
    f32x4 a = *(const f32x4*)(in + idx);
    f32x4 b = *(const f32x4*)(in + idx + 4);
    bf16x8 o;
#pragma unroll
    for (int i = 0; i < 4; ++i) { o[i] = (__bf16)a[i]; o[i + 4] = (__bf16)b[i]; }
    *(bf16x8*)(out + idx) = o;
}

// ---------------------------------------------------------------------------
// Time-shift mix: out = x*m + last_x*(1-m)  (f32 in, bf16 out for MFMA).
// ---------------------------------------------------------------------------
__global__ void mix_kernel(const float* __restrict__ x,
                           const float* __restrict__ mixw,
                           __bf16* __restrict__ out,
                           int T, int D, long total) {
    long idx = ((long)blockIdx.x * blockDim.x + threadIdx.x) * 8;
    if (idx >= total) return;
    int d = (int)(idx % D);
    long bt = idx / D;
    int t = (int)(bt % T);

    f32x4 x0 = *(const f32x4*)(x + idx);
    f32x4 x1 = *(const f32x4*)(x + idx + 4);
    f32x4 l0 = {}, l1 = {};
    if (t != 0) {
        l0 = *(const f32x4*)(x + idx - D);
        l1 = *(const f32x4*)(x + idx - D + 4);
    }
    f32x4 m0 = *(const f32x4*)(mixw + d);
    f32x4 m1 = *(const f32x4*)(mixw + d + 4);
    bf16x8 o;
#pragma unroll
    for (int i = 0; i < 4; ++i) {
        o[i]     = (__bf16)(x0[i] * m0[i] + l0[i] * (1.0f - m0[i]));
        o[i + 4] = (__bf16)(x1[i] * m1[i] + l1[i] * (1.0f - m1[i]));
    }
    *(bf16x8*)(out + idx) = o;
}

// ---------------------------------------------------------------------------
// GEMM, B^T layout: C[m,n] = sum_k A[m,k]*Bt[n,k]. A: MxK bf16 row-major,
// Bt: NxK bf16 row-major, C: MxN (f32 or bf16). 256 thr / 4 waves, each wave
// a 64x64 quadrant via 4x4 mfma_f32_16x16x32_bf16. Staging via
// global_load_lds width=16; XOR chunk swizzle permutes which global 16B chunk
// each lane FETCHES (deposit stays contiguous base+lane*16), so the
// ds_read_b128 fragment reads spread across bank groups (2-way = free, m136).
// ---------------------------------------------------------------------------
template <typename CT>
__global__ __launch_bounds__(256, 3)
void gemm_bt(const __bf16* __restrict__ A, const __bf16* __restrict__ Bt,
             CT* __restrict__ C, int M, int N, int K) {
    __shared__ __align__(16) __bf16 sA[BM * BK];
    __shared__ __align__(16) __bf16 sB[BN * BK];

    const int tid  = threadIdx.x;
    const int lane = tid & 63;
    const int wave = tid >> 6;
    const int m0 = blockIdx.y * BM;
    const int n0 = blockIdx.x * BN;
    const int wm = (wave & 1) * 64;
    const int wn = (wave >> 1) * 64;

    const int l8 = lane >> 3;          // row within 8-row group
    const int c8 = lane & 7;           // LDS chunk slot this lane deposits to
    const int cg = c8 ^ l8;            // swizzled global chunk to fetch

    const int q  = lane >> 4;          // MFMA quad
    const int ml = lane & 15;          // MFMA row/col within 16

    f32x4 acc[4][4] = {};

    for (int k0 = 0; k0 < K; k0 += BK) {
#pragma unroll
        for (int i = 0; i < 4; ++i) {
            const int cl  = wave * 4 + i;       // chunk-row group (wave-uniform)
            const int row = cl * 8 + l8;
            const __bf16* gA = A  + (long)(m0 + row) * K + (k0 + cg * 8);
            const __bf16* gB = Bt + (long)(n0 + row) * K + (k0 + cg * 8);
            __builtin_amdgcn_global_load_lds(
                (const __attribute__((address_space(1))) void*)gA,
                (__attribute__((address_space(3))) void*)(sA + cl * 512), 16, 0, 0);
            __builtin_amdgcn_global_load_lds(
                (const __attribute__((address_space(1))) void*)gB,
                (__attribute__((address_space(3))) void*)(sB + cl * 512), 16, 0, 0);
        }
        __syncthreads();

#pragma unroll
        for (int kk = 0; kk < BK; kk += 32) {
            bf16x8 af[4], bfr[4];
#pragma unroll
            for (int i = 0; i < 4; ++i) {
                int row = wm + i * 16 + ml;
                int cl  = ((kk >> 3) + q) ^ (row & 7);
                af[i] = *(const bf16x8*)(sA + row * BK + cl * 8);
            }
#pragma unroll
            for (int j = 0; j < 4; ++j) {
                int row = wn + j * 16 + ml;
                int cl  = ((kk >> 3) + q) ^ (row & 7);
                bfr[j] = *(const bf16x8*)(sB + row * BK + cl * 8);
            }
#pragma unroll
            for (int i = 0; i < 4; ++i)
#pragma unroll
                for (int j = 0; j < 4; ++j)
                    acc[i][j] = __builtin_amdgcn_mfma_f32_16x16x32_bf16(
                        af[i], bfr[j], acc[i][j], 0, 0, 0);
        }
        __syncthreads();
    }

    // C/D layout: col = lane&15, row = quad*4 + reg (verified m89/m91)
#pragma unroll
    for (int i = 0; i < 4; ++i)
#pragma unroll
        for (int j = 0; j < 4; ++j)
#pragma unroll
            for (int rg = 0; rg < 4; ++rg) {
                int row = m0 + wm + i * 16 + q * 4 + rg;
                int col = n0 + wn + j * 16 + ml;
                C[(long)row * N + col] = (CT)acc[i][j][rg];
            }
}

// ---------------------------------------------------------------------------
// WKV scan: one thread per (b,d) channel, serial over T. Stabilized log-space
// recurrence identical to the reference. Depth-8 double-buffered register
// prefetch. Fuses sigmoid(r) gate; emits bf16 (wkv*sr) for the output GEMM.
// ---------------------------------------------------------------------------
template <typename ST>
__global__ void wkv_kernel(const ST* __restrict__ kk, const ST* __restrict__ vv,
                           const __bf16* __restrict__ rr,
                           const float* __restrict__ td,
                           const float* __restrict__ tf,
                           __bf16* __restrict__ out, int Bn, int T, int D) {
    int gid = blockIdx.x * blockDim.x + threadIdx.x;
    if (gid >= Bn * D) return;
    int d = gid % D;
    int b = gid / D;

    float u = tf[d];
    float w = __expf(td[d]);
    float alpha = 0.f, beta = 0.f, eps = -1e30f;
    long base = (long)b * T * D + d;

    const int P = 8;
    float kb0[P], vb0[P], rb0[P], kb1[P], vb1[P], rb1[P];

    auto step = [&](float kt, float vt, float rt, int tIdx) {
        float ww  = u + kt;
        float tau = fmaxf(eps, ww);
        float e1  = __expf(eps - tau);
        float e2  = __expf(ww - tau);
        float num = e1 * alpha + e2 * vt;
        float den = e1 * beta + e2;
        float o_  = num * __builtin_amdgcn_rcpf(den);
        float ww2  = eps - w;
        float tau2 = fmaxf(ww2, kt);
        float e1b  = __expf(ww2 - tau2);
        float e2b  = __expf(kt - tau2);
        alpha = e1b * alpha + e2b * vt;
        beta  = e1b * beta + e2b;
        eps   = tau2;
        float sr = __builtin_amdgcn_rcpf(1.0f + __expf(-rt));
        out[base + (long)tIdx * D] = (__bf16)(o_ * sr);
    };

#pragma unroll
    for (int j = 0; j < P; ++j) {
        long o = base + (long)j * D;
        kb0[j] = (float)kk[o]; vb0[j] = (float)vv[o]; rb0[j] = (float)rr[o];
    }
    for (int t0 = 0; t0 < T; t0 += 2 * P) {
#pragma unroll
        for (int j = 0; j < P; ++j) {
            long o = base + (long)(t0 + P + j) * D;
            kb1[j] = (float)kk[o]; vb1[j] = (float)vv[o]; rb1[j] = (float)rr[o];
        }
#pragma unroll
        for (int j = 0; j < P; ++j) step(kb0[j], vb0[j], rb0[j], t0 + j);
        if (t0 + 2 * P < T) {
#pragma unroll
            for (int j = 0; j < P; ++j) {
                long o = base + (long)(t0 + 2 * P + j) * D;
                kb0[j] = (float)kk[o]; vb0[j] = (float)vv[o]; rb0[j] = (float)rr[o];
            }
        }
#pragma unroll
        for (int j = 0; j < P; ++j) step(kb1[j], vb1[j], rb1[j], t0 + P + j);
    }
}

// ---------------------------------------------------------------------------
extern "C" void kernel_launch(void* const* d_in, const int* in_sizes, int n_in,
                              void* d_out, int out_size, void* d_ws, size_t ws_size,
                              hipStream_t stream) {
    const float* x  = (const float*)d_in[0];
    const float* td = (const float*)d_in[1];
    const float* tf = (const float*)d_in[2];
    const float* mk = (const float*)d_in[3];
    const float* mv = (const float*)d_in[4];
    const float* mr = (const float*)d_in[5];
    const float* Wk = (const float*)d_in[6];
    const float* Wv = (const float*)d_in[7];
    const float* Wr = (const float*)d_in[8];
    const float* Wo = (const float*)d_in[9];
    float* out = (float*)d_out;

    const int D = in_sizes[1];                    // 2048
    const int T = 2048;
    const long total = (long)in_sizes[0];         // B*T*D
    const int Bn = (int)(total / ((long)T * D));  // 4
    const int M = Bn * T;

    // workspace layout
    char* p = (char*)d_ws;
    __bf16* xm  = (__bf16*)p;            p += total * 2;       // mix / wkv*sr buf
    __bf16* wkb = (__bf16*)p;            p += (long)D * D * 2;
    __bf16* wvb = (__bf16*)p;            p += (long)D * D * 2;
    __bf16* wrb = (__bf16*)p;            p += (long)D * D * 2;
    __bf16* wob = (__bf16*)p;            p += (long)D * D * 2;
    size_t base_need = (size_t)(p - (char*)d_ws);
    bool use_f32 = ws_size >= base_need + (size_t)total * 4 * 2 + (size_t)total * 2;

    dim3 mixGrid((unsigned)((total / 8 + 255) / 256));
    dim3 cvtGrid((unsigned)(((long)D * D / 8 + 255) / 256));
    dim3 gemmGrid(D / BN, M / BM);
    dim3 scanGrid((Bn * D + 255) / 256);

    cvt_bf16<<<cvtGrid, 256, 0, stream>>>(Wk, wkb, (long)D * D);
    cvt_bf16<<<cvtGrid, 256, 0, stream>>>(Wv, wvb, (long)D * D);
    cvt_bf16<<<cvtGrid, 256, 0, stream>>>(Wr, wrb, (long)D * D);
    cvt_bf16<<<cvtGrid, 256, 0, stream>>>(Wo, wob, (long)D * D);

    if (use_f32) {
        float*  kf = (float*)p;          p += total * 4;
        float*  vf = (float*)p;          p += total * 4;
        __bf16* rb = (__bf16*)p;

        mix_kernel<<<mixGrid, 256, 0, stream>>>(x, mk, xm, T, D, total);
        gemm_bt<float><<<gemmGrid, 256, 0, stream>>>(xm, wkb, kf, M, D, D);
        mix_kernel<<<mixGrid, 256, 0, stream>>>(x, mv, xm, T, D, total);
        gemm_bt<float><<<gemmGrid, 256, 0, stream>>>(xm, wvb, vf, M, D, D);
        mix_kernel<<<mixGrid, 256, 0, stream>>>(x, mr, xm, T, D, total);
        gemm_bt<__bf16><<<gemmGrid, 256, 0, stream>>>(xm, wrb, rb, M, D, D);
        wkv_kernel<float><<<scanGrid, 256, 0, stream>>>(kf, vf, rb, td, tf, xm, Bn, T, D);
        gemm_bt<float><<<gemmGrid, 256, 0, stream>>>(xm, wob, out, M, D, D);
    } else {
        __bf16* kb = (__bf16*)p;         p += total * 2;
        __bf16* vb = (__bf16*)p;         p += total * 2;
        __bf16* rb = (__bf16*)p;

        mix_kernel<<<mixGrid, 256, 0, stream>>>(x, mk, xm, T, D, total);
        gemm_bt<__bf16><<<gemmGrid, 256, 0, stream>>>(xm, wkb, kb, M, D, D);
        mix_kernel<<<mixGrid, 256, 0, stream>>>(x, mv, xm, T, D, total);
        gemm_bt<__bf16><<<gemmGrid, 256, 0, stream>>>(xm, wvb, vb, M, D, D);
        mix_kernel<<<mixGrid, 256, 0, stream>>>(x, mr, xm, T, D, total);
        gemm_bt<__bf16><<<gemmGrid, 256, 0, stream>>>(xm, wrb, rb, M, D, D);
        wkv_kernel<__bf16><<<scanGrid, 256, 0, stream>>>(kb, vb, rb, td, tf, xm, Bn, T, D);
        gemm_bt<float><<<gemmGrid, 256, 0, stream>>>(xm, wob, out, M, D, D);
    }
}

// Round 3
// 584.552 us; speedup vs baseline: 1.4620x; 1.4620x over previous
//
#include <hip/hip_runtime.h>
#include <stdint.h>

typedef __bf16 bf16x8 __attribute__((ext_vector_type(8)));
typedef float f32x4 __attribute__((ext_vector_type(4)));

#define BM 128
#define BN 128
#define BK 64

// ---------------------------------------------------------------------------
// f32 -> bf16 conversion (weights). 8 elements/thread.
// ---------------------------------------------------------------------------
__global__ void cvt_bf16(const float* __restrict__ in, __bf16* __restrict__ out,
                         long n) {
    long idx = ((long)blockIdx.x * blockDim.x + threadIdx.x) * 8;
    if (idx >= n) return;
    f32x4 a = *(const f32x4*)(in + idx);
    f32x4 b = *(const f32x4*)(in + idx + 4);
    bf16x8 o;
#pragma unroll
    for (int i = 0; i < 4; ++i) { o[i] = (__bf16)a[i]; o[i + 4] = (__bf16)b[i]; }
    *(bf16x8*)(out + idx) = o;
}

// ---------------------------------------------------------------------------
// Time-shift mix: out = x*m + last_x*(1-m)  (f32 in, bf16 out for MFMA).
// ---------------------------------------------------------------------------
__global__ void mix_kernel(const float* __restrict__ x,
                           const float* __restrict__ mixw,
                           __bf16* __restrict__ out,
                           int T, int D, long total) {
    long idx = ((long)blockIdx.x * blockDim.x + threadIdx.x) * 8;
    if (idx >= total) return;
    int d = (int)(idx % D);
    long bt = idx / D;
    int t = (int)(bt % T);

    f32x4 x0 = *(const f32x4*)(x + idx);
    f32x4 x1 = *(const f32x4*)(x + idx + 4);
    f32x4 l0 = {}, l1 = {};
    if (t != 0) {
        l0 = *(const f32x4*)(x + idx - D);
        l1 = *(const f32x4*)(x + idx - D + 4);
    }
    f32x4 m0 = *(const f32x4*)(mixw + d);
    f32x4 m1 = *(const f32x4*)(mixw + d + 4);
    bf16x8 o;
#pragma unroll
    for (int i = 0; i < 4; ++i) {
        o[i]     = (__bf16)(x0[i] * m0[i] + l0[i] * (1.0f - m0[i]));
        o[i + 4] = (__bf16)(x1[i] * m1[i] + l1[i] * (1.0f - m1[i]));
    }
    *(bf16x8*)(out + idx) = o;
}

// ---------------------------------------------------------------------------
// GEMM, B^T layout (verified m97-ladder structure; unchanged from round 2).
// ---------------------------------------------------------------------------
template <typename CT>
__global__ __launch_bounds__(256, 3)
void gemm_bt(const __bf16* __restrict__ A, const __bf16* __restrict__ Bt,
             CT* __restrict__ C, int M, int N, int K) {
    __shared__ __align__(16) __bf16 sA[BM * BK];
    __shared__ __align__(16) __bf16 sB[BN * BK];

    const int tid  = threadIdx.x;
    const int lane = tid & 63;
    const int wave = tid >> 6;
    const int m0 = blockIdx.y * BM;
    const int n0 = blockIdx.x * BN;
    const int wm = (wave & 1) * 64;
    const int wn = (wave >> 1) * 64;

    const int l8 = lane >> 3;
    const int c8 = lane & 7;
    const int cg = c8 ^ l8;

    const int q  = lane >> 4;
    const int ml = lane & 15;

    f32x4 acc[4][4] = {};

    for (int k0 = 0; k0 < K; k0 += BK) {
#pragma unroll
        for (int i = 0; i < 4; ++i) {
            const int cl  = wave * 4 + i;
            const int row = cl * 8 + l8;
            const __bf16* gA = A  + (long)(m0 + row) * K + (k0 + cg * 8);
            const __bf16* gB = Bt + (long)(n0 + row) * K + (k0 + cg * 8);
            __builtin_amdgcn_global_load_lds(
                (const __attribute__((address_space(1))) void*)gA,
                (__attribute__((address_space(3))) void*)(sA + cl * 512), 16, 0, 0);
            __builtin_amdgcn_global_load_lds(
                (const __attribute__((address_space(1))) void*)gB,
                (__attribute__((address_space(3))) void*)(sB + cl * 512), 16, 0, 0);
        }
        __syncthreads();

#pragma unroll
        for (int kk = 0; kk < BK; kk += 32) {
            bf16x8 af[4], bfr[4];
#pragma unroll
            for (int i = 0; i < 4; ++i) {
                int row = wm + i * 16 + ml;
                int cl  = ((kk >> 3) + q) ^ (row & 7);
                af[i] = *(const bf16x8*)(sA + row * BK + cl * 8);
            }
#pragma unroll
            for (int j = 0; j < 4; ++j) {
                int row = wn + j * 16 + ml;
                int cl  = ((kk >> 3) + q) ^ (row & 7);
                bfr[j] = *(const bf16x8*)(sB + row * BK + cl * 8);
            }
#pragma unroll
            for (int i = 0; i < 4; ++i)
#pragma unroll
                for (int j = 0; j < 4; ++j)
                    acc[i][j] = __builtin_amdgcn_mfma_f32_16x16x32_bf16(
                        af[i], bfr[j], acc[i][j], 0, 0, 0);
        }
        __syncthreads();
    }

#pragma unroll
    for (int i = 0; i < 4; ++i)
#pragma unroll
        for (int j = 0; j < 4; ++j)
#pragma unroll
            for (int rg = 0; rg < 4; ++rg) {
                int row = m0 + wm + i * 16 + q * 4 + rg;
                int col = n0 + wn + j * 16 + ml;
                C[(long)row * N + col] = (CT)acc[i][j][rg];
            }
}

// ---------------------------------------------------------------------------
// Chunk-parallel WKV scan.
// The unstabilized recurrence A_t = e^{-w}A_{t-1} + e^{k_t}v_t (channel-
// constant decay) chunk-decomposes exactly: A_end = e^{-wL} A_in + A_loc.
// pass1: per-chunk local (alpha,beta,eps); combine: serial C-step fold giving
// each chunk's inbound state; pass2: exact replay with outputs + sigmoid(r).
// Thread layout gid = c*B*D + b*D + d -> all global loads coalesced over d.
// ---------------------------------------------------------------------------
template <typename ST>
__global__ void wkv_pass1(const ST* __restrict__ kk, const ST* __restrict__ vv,
                          const float* __restrict__ td,
                          float* __restrict__ al, float* __restrict__ bl,
                          float* __restrict__ el,
                          int Bn, int T, int D, int C, int L) {
    int gid = blockIdx.x * blockDim.x + threadIdx.x;
    int BD = Bn * D;
    if (gid >= BD * C) return;
    int c  = gid / BD;
    int bd = gid - c * BD;
    int b  = bd / D;
    int d  = bd - b * D;

    float w = __expf(td[d]);
    float alpha = 0.f, beta = 0.f, eps = -1e30f;
    long base = ((long)b * T + (long)c * L) * D + d;

    const int P = 8;
    float kb0[P], vb0[P], kb1[P], vb1[P];

    auto step = [&](float kt, float vt) {
        float ww2  = eps - w;
        float tau2 = fmaxf(ww2, kt);
        float e1b  = __expf(ww2 - tau2);
        float e2b  = __expf(kt - tau2);
        alpha = e1b * alpha + e2b * vt;
        beta  = e1b * beta + e2b;
        eps   = tau2;
    };

#pragma unroll
    for (int j = 0; j < P; ++j) {
        long o = base + (long)j * D;
        kb0[j] = (float)kk[o]; vb0[j] = (float)vv[o];
    }
    for (int t0 = 0; t0 < L; t0 += 2 * P) {
#pragma unroll
        for (int j = 0; j < P; ++j) {
            long o = base + (long)(t0 + P + j) * D;
            kb1[j] = (float)kk[o]; vb1[j] = (float)vv[o];
        }
#pragma unroll
        for (int j = 0; j < P; ++j) step(kb0[j], vb0[j]);
        if (t0 + 2 * P < L) {
#pragma unroll
            for (int j = 0; j < P; ++j) {
                long o = base + (long)(t0 + 2 * P + j) * D;
                kb0[j] = (float)kk[o]; vb0[j] = (float)vv[o];
            }
        }
#pragma unroll
        for (int j = 0; j < P; ++j) step(kb1[j], vb1[j]);
    }
    al[gid] = alpha; bl[gid] = beta; el[gid] = eps;
}

__global__ void wkv_combine(const float* __restrict__ al, const float* __restrict__ bl,
                            const float* __restrict__ el, const float* __restrict__ td,
                            float* __restrict__ ai, float* __restrict__ bi,
                            float* __restrict__ ei,
                            int Bn, int D, int C, int L) {
    int bd = blockIdx.x * blockDim.x + threadIdx.x;
    int BD = Bn * D;
    if (bd >= BD) return;
    int d = bd % D;
    float wL = __expf(td[d]) * (float)L;
    float a = 0.f, b2 = 0.f, e = -1e30f;
    for (int c = 0; c < C; ++c) {
        int idx = c * BD + bd;
        ai[idx] = a; bi[idx] = b2; ei[idx] = e;
        float ed  = e - wL;
        float la = al[idx], lb = bl[idx], le = el[idx];
        float tau = fmaxf(ed, le);
        float e1  = __expf(ed - tau);
        float e2  = __expf(le - tau);
        a  = a * e1 + la * e2;
        b2 = b2 * e1 + lb * e2;
        e  = tau;
    }
}

template <typename ST>
__global__ void wkv_pass2(const ST* __restrict__ kk, const ST* __restrict__ vv,
                          const __bf16* __restrict__ rr,
                          const float* __restrict__ td, const float* __restrict__ tf,
                          const float* __restrict__ ai, const float* __restrict__ bi,
                          const float* __restrict__ ei,
                          __bf16* __restrict__ out,
                          int Bn, int T, int D, int C, int L) {
    int gid = blockIdx.x * blockDim.x + threadIdx.x;
    int BD = Bn * D;
    if (gid >= BD * C) return;
    int c  = gid / BD;
    int bd = gid - c * BD;
    int b  = bd / D;
    int d  = bd - b * D;

    float u = tf[d];
    float w = __expf(td[d]);
    float alpha = ai[gid], beta = bi[gid], eps = ei[gid];
    long base = ((long)b * T + (long)c * L) * D + d;

    const int P = 8;
    float kb0[P], vb0[P], rb0[P], kb1[P], vb1[P], rb1[P];

    auto step = [&](float kt, float vt, float rt, int tIdx) {
        float ww  = u + kt;
        float tau = fmaxf(eps, ww);
        float e1  = __expf(eps - tau);
        float e2  = __expf(ww - tau);
        float num = e1 * alpha + e2 * vt;
        float den = e1 * beta + e2;
        float o_  = num * __builtin_amdgcn_rcpf(den);
        float ww2  = eps - w;
        float tau2 = fmaxf(ww2, kt);
        float e1b  = __expf(ww2 - tau2);
        float e2b  = __expf(kt - tau2);
        alpha = e1b * alpha + e2b * vt;
        beta  = e1b * beta + e2b;
        eps   = tau2;
        float sr = __builtin_amdgcn_rcpf(1.0f + __expf(-rt));
        out[base + (long)tIdx * D] = (__bf16)(o_ * sr);
    };

#pragma unroll
    for (int j = 0; j < P; ++j) {
        long o = base + (long)j * D;
        kb0[j] = (float)kk[o]; vb0[j] = (float)vv[o]; rb0[j] = (float)rr[o];
    }
    for (int t0 = 0; t0 < L; t0 += 2 * P) {
#pragma unroll
        for (int j = 0; j < P; ++j) {
            long o = base + (long)(t0 + P + j) * D;
            kb1[j] = (float)kk[o]; vb1[j] = (float)vv[o]; rb1[j] = (float)rr[o];
        }
#pragma unroll
        for (int j = 0; j < P; ++j) step(kb0[j], vb0[j], rb0[j], t0 + j);
        if (t0 + 2 * P < L) {
#pragma unroll
            for (int j = 0; j < P; ++j) {
                long o = base + (long)(t0 + 2 * P + j) * D;
                kb0[j] = (float)kk[o]; vb0[j] = (float)vv[o]; rb0[j] = (float)rr[o];
            }
        }
#pragma unroll
        for (int j = 0; j < P; ++j) step(kb1[j], vb1[j], rb1[j], t0 + P + j);
    }
}

// ---------------------------------------------------------------------------
extern "C" void kernel_launch(void* const* d_in, const int* in_sizes, int n_in,
                              void* d_out, int out_size, void* d_ws, size_t ws_size,
                              hipStream_t stream) {
    const float* x  = (const float*)d_in[0];
    const float* td = (const float*)d_in[1];
    const float* tf = (const float*)d_in[2];
    const float* mk = (const float*)d_in[3];
    const float* mv = (const float*)d_in[4];
    const float* mr = (const float*)d_in[5];
    const float* Wk = (const float*)d_in[6];
    const float* Wv = (const float*)d_in[7];
    const float* Wr = (const float*)d_in[8];
    const float* Wo = (const float*)d_in[9];
    float* out = (float*)d_out;

    const int D = in_sizes[1];                    // 2048
    const int T = 2048;
    const long total = (long)in_sizes[0];         // B*T*D
    const int Bn = (int)(total / ((long)T * D));  // 4
    const int M = Bn * T;
    const int C = 32;                             // scan chunks per channel
    const int L = T / C;                          // 64
    const int BD = Bn * D;
    const int S = BD * C;

    // workspace layout
    char* p = (char*)d_ws;
    __bf16* xm  = (__bf16*)p;            p += total * 2;       // mix / wkv*sr buf
    __bf16* wkb = (__bf16*)p;            p += (long)D * D * 2;
    __bf16* wvb = (__bf16*)p;            p += (long)D * D * 2;
    __bf16* wrb = (__bf16*)p;            p += (long)D * D * 2;
    __bf16* wob = (__bf16*)p;            p += (long)D * D * 2;
    size_t base_need = (size_t)(p - (char*)d_ws);
    bool use_f32 = ws_size >= base_need + (size_t)total * 4 * 2 + (size_t)total * 2;

    // scan state arrays alias wkb+wvb (dead by the time the scan runs;
    // single-stream ordering makes this safe). 6*S*4 = 6.3 MB < 16.8 MB.
    float* st = (float*)wkb;
    float *al = st, *bl = st + S, *el = st + 2 * S;
    float *ai = st + 3 * S, *bi = st + 4 * S, *ei = st + 5 * S;

    dim3 mixGrid((unsigned)((total / 8 + 255) / 256));
    dim3 cvtGrid((unsigned)(((long)D * D / 8 + 255) / 256));
    dim3 gemmGrid(D / BN, M / BM);
    dim3 p12Grid((S + 255) / 256);
    dim3 cmbGrid((BD + 255) / 256);

    cvt_bf16<<<cvtGrid, 256, 0, stream>>>(Wk, wkb, (long)D * D);
    cvt_bf16<<<cvtGrid, 256, 0, stream>>>(Wv, wvb, (long)D * D);
    cvt_bf16<<<cvtGrid, 256, 0, stream>>>(Wr, wrb, (long)D * D);
    cvt_bf16<<<cvtGrid, 256, 0, stream>>>(Wo, wob, (long)D * D);

    if (use_f32) {
        float*  kf = (float*)p;          p += total * 4;
        float*  vf = (float*)p;          p += total * 4;
        __bf16* rb = (__bf16*)p;

        mix_kernel<<<mixGrid, 256, 0, stream>>>(x, mk, xm, T, D, total);
        gemm_bt<float><<<gemmGrid, 256, 0, stream>>>(xm, wkb, kf, M, D, D);
        mix_kernel<<<mixGrid, 256, 0, stream>>>(x, mv, xm, T, D, total);
        gemm_bt<float><<<gemmGrid, 256, 0, stream>>>(xm, wvb, vf, M, D, D);
        mix_kernel<<<mixGrid, 256, 0, stream>>>(x, mr, xm, T, D, total);
        gemm_bt<__bf16><<<gemmGrid, 256, 0, stream>>>(xm, wrb, rb, M, D, D);

        wkv_pass1<float><<<p12Grid, 256, 0, stream>>>(kf, vf, td, al, bl, el,
                                                      Bn, T, D, C, L);
        wkv_combine<<<cmbGrid, 256, 0, stream>>>(al, bl, el, td, ai, bi, ei,
                                                 Bn, D, C, L);
        wkv_pass2<float><<<p12Grid, 256, 0, stream>>>(kf, vf, rb, td, tf,
                                                      ai, bi, ei, xm,
                                                      Bn, T, D, C, L);
        gemm_bt<float><<<gemmGrid, 256, 0, stream>>>(xm, wob, out, M, D, D);
    } else {
        __bf16* kb = (__bf16*)p;         p += total * 2;
        __bf16* vb = (__bf16*)p;         p += total * 2;
        __bf16* rb = (__bf16*)p;

        mix_kernel<<<mixGrid, 256, 0, stream>>>(x, mk, xm, T, D, total);
        gemm_bt<__bf16><<<gemmGrid, 256, 0, stream>>>(xm, wkb, kb, M, D, D);
        mix_kernel<<<mixGrid, 256, 0, stream>>>(x, mv, xm, T, D, total);
        gemm_bt<__bf16><<<gemmGrid, 256, 0, stream>>>(xm, wvb, vb, M, D, D);
        mix_kernel<<<mixGrid, 256, 0, stream>>>(x, mr, xm, T, D, total);
        gemm_bt<__bf16><<<gemmGrid, 256, 0, stream>>>(xm, wrb, rb, M, D, D);

        wkv_pass1<__bf16><<<p12Grid, 256, 0, stream>>>(kb, vb, td, al, bl, el,
                                                       Bn, T, D, C, L);
        wkv_combine<<<cmbGrid, 256, 0, stream>>>(al, bl, el, td, ai, bi, ei,
                                                 Bn, D, C, L);
        wkv_pass2<__bf16><<<p12Grid, 256, 0, stream>>>(kb, vb, rb, td, tf,
                                                       ai, bi, ei, xm,
                                                       Bn, T, D, C, L);
        gemm_bt<float><<<gemmGrid, 256, 0, stream>>>(xm, wob, out, M, D, D);
    }
}

// Round 4
// 544.267 us; speedup vs baseline: 1.5703x; 1.0740x over previous
//
#include <hip/hip_runtime.h>
#include <stdint.h>

typedef __bf16 bf16x8 __attribute__((ext_vector_type(8)));
typedef float f32x4 __attribute__((ext_vector_type(4)));

#define BM 128
#define BN 128
#define BK 64

// ---------------------------------------------------------------------------
// Fused f32->bf16 conversion of all four weight matrices (each DD elements).
// ---------------------------------------------------------------------------
__global__ void cvt4_bf16(const float* __restrict__ w0, const float* __restrict__ w1,
                          const float* __restrict__ w2, const float* __restrict__ w3,
                          __bf16* __restrict__ o0, __bf16* __restrict__ o1,
                          __bf16* __restrict__ o2, __bf16* __restrict__ o3,
                          long DD) {
    long idx = ((long)blockIdx.x * blockDim.x + threadIdx.x) * 8;
    if (idx >= 4 * DD) return;
    int w = (int)(idx / DD);            // block-uniform (DD % 2048 == 0)
    long off = idx - (long)w * DD;
    const float* in = (w == 0) ? w0 : (w == 1) ? w1 : (w == 2) ? w2 : w3;
    __bf16* out     = (w == 0) ? o0 : (w == 1) ? o1 : (w == 2) ? o2 : o3;
    f32x4 a = *(const f32x4*)(in + off);
    f32x4 b = *(const f32x4*)(in + off + 4);
    bf16x8 o;
#pragma unroll
    for (int i = 0; i < 4; ++i) { o[i] = (__bf16)a[i]; o[i + 4] = (__bf16)b[i]; }
    *(bf16x8*)(out + off) = o;
}

// ---------------------------------------------------------------------------
// Fused time-shift mix: reads x once, emits all three mixed matrices (bf16).
// out_* = x*m + last_x*(1-m), last_x = token-shifted x (zeros at t==0).
// ---------------------------------------------------------------------------
__global__ void mix3_kernel(const float* __restrict__ x,
                            const float* __restrict__ mk,
                            const float* __restrict__ mv,
                            const float* __restrict__ mr,
                            __bf16* __restrict__ ok, __bf16* __restrict__ ov,
                            __bf16* __restrict__ orr,
                            int T, int D, long total) {
    long idx = ((long)blockIdx.x * blockDim.x + threadIdx.x) * 8;
    if (idx >= total) return;
    int d = (int)(idx % D);
    long bt = idx / D;
    int t = (int)(bt % T);

    f32x4 x0 = *(const f32x4*)(x + idx);
    f32x4 x1 = *(const f32x4*)(x + idx + 4);
    f32x4 l0 = {}, l1 = {};
    if (t != 0) {
        l0 = *(const f32x4*)(x + idx - D);
        l1 = *(const f32x4*)(x + idx - D + 4);
    }
    const float* mw[3] = {mk, mv, mr};
    __bf16* ow[3] = {ok, ov, orr};
#pragma unroll
    for (int s = 0; s < 3; ++s) {
        f32x4 m0 = *(const f32x4*)(mw[s] + d);
        f32x4 m1 = *(const f32x4*)(mw[s] + d + 4);
        bf16x8 o;
#pragma unroll
        for (int i = 0; i < 4; ++i) {
            o[i]     = (__bf16)(x0[i] * m0[i] + l0[i] * (1.0f - m0[i]));
            o[i + 4] = (__bf16)(x1[i] * m1[i] + l1[i] * (1.0f - m1[i]));
        }
        *(bf16x8*)(ow[s] + idx) = o;
    }
}

// ---------------------------------------------------------------------------
// GEMM body (m97-ladder structure, verified rounds 2-3). Shared by the
// single and z-batched entry points via forceinline.
// ---------------------------------------------------------------------------
template <typename CT>
__device__ __attribute__((always_inline))
void gemm_body(const __bf16* __restrict__ A, const __bf16* __restrict__ Bt,
               CT* __restrict__ C, int M, int N, int K) {
    __shared__ __align__(16) __bf16 sA[BM * BK];
    __shared__ __align__(16) __bf16 sB[BN * BK];

    const int tid  = threadIdx.x;
    const int lane = tid & 63;
    const int wave = tid >> 6;
    const int m0 = blockIdx.y * BM;
    const int n0 = blockIdx.x * BN;
    const int wm = (wave & 1) * 64;
    const int wn = (wave >> 1) * 64;

    const int l8 = lane >> 3;
    const int c8 = lane & 7;
    const int cg = c8 ^ l8;

    const int q  = lane >> 4;
    const int ml = lane & 15;

    f32x4 acc[4][4] = {};

    for (int k0 = 0; k0 < K; k0 += BK) {
#pragma unroll
        for (int i = 0; i < 4; ++i) {
            const int cl  = wave * 4 + i;
            const int row = cl * 8 + l8;
            const __bf16* gA = A  + (long)(m0 + row) * K + (k0 + cg * 8);
            const __bf16* gB = Bt + (long)(n0 + row) * K + (k0 + cg * 8);
            __builtin_amdgcn_global_load_lds(
                (const __attribute__((address_space(1))) void*)gA,
                (__attribute__((address_space(3))) void*)(sA + cl * 512), 16, 0, 0);
            __builtin_amdgcn_global_load_lds(
                (const __attribute__((address_space(1))) void*)gB,
                (__attribute__((address_space(3))) void*)(sB + cl * 512), 16, 0, 0);
        }
        __syncthreads();

#pragma unroll
        for (int kk = 0; kk < BK; kk += 32) {
            bf16x8 af[4], bfr[4];
#pragma unroll
            for (int i = 0; i < 4; ++i) {
                int row = wm + i * 16 + ml;
                int cl  = ((kk >> 3) + q) ^ (row & 7);
                af[i] = *(const bf16x8*)(sA + row * BK + cl * 8);
            }
#pragma unroll
            for (int j = 0; j < 4; ++j) {
                int row = wn + j * 16 + ml;
                int cl  = ((kk >> 3) + q) ^ (row & 7);
                bfr[j] = *(const bf16x8*)(sB + row * BK + cl * 8);
            }
#pragma unroll
            for (int i = 0; i < 4; ++i)
#pragma unroll
                for (int j = 0; j < 4; ++j)
                    acc[i][j] = __builtin_amdgcn_mfma_f32_16x16x32_bf16(
                        af[i], bfr[j], acc[i][j], 0, 0, 0);
        }
        __syncthreads();
    }

#pragma unroll
    for (int i = 0; i < 4; ++i)
#pragma unroll
        for (int j = 0; j < 4; ++j)
#pragma unroll
            for (int rg = 0; rg < 4; ++rg) {
                int row = m0 + wm + i * 16 + q * 4 + rg;
                int col = n0 + wn + j * 16 + ml;
                C[(long)row * N + col] = (CT)acc[i][j][rg];
            }
}

template <typename CT>
__global__ __launch_bounds__(256, 3)
void gemm_bt(const __bf16* __restrict__ A, const __bf16* __restrict__ Bt,
             CT* __restrict__ C, int M, int N, int K) {
    gemm_body<CT>(A, Bt, C, M, N, K);
}

// z-batched pair (v and r GEMMs), both bf16 outputs.
__global__ __launch_bounds__(256, 3)
void gemm_bt2(const __bf16* __restrict__ A0, const __bf16* __restrict__ A1,
              const __bf16* __restrict__ B0, const __bf16* __restrict__ B1,
              __bf16* __restrict__ C0, __bf16* __restrict__ C1,
              int M, int N, int K) {
    if (blockIdx.z == 0) gemm_body<__bf16>(A0, B0, C0, M, N, K);
    else                 gemm_body<__bf16>(A1, B1, C1, M, N, K);
}

// ---------------------------------------------------------------------------
// Chunk-parallel WKV scan (verified round 3). k is f32 (exponentiated —
// precision-critical); v, r are bf16 (enter linearly / sigmoid-damped).
// ---------------------------------------------------------------------------
__global__ void wkv_pass1(const float* __restrict__ kk, const __bf16* __restrict__ vv,
                          const float* __restrict__ td,
                          float* __restrict__ al, float* __restrict__ bl,
                          float* __restrict__ el,
                          int Bn, int T, int D, int C, int L) {
    int gid = blockIdx.x * blockDim.x + threadIdx.x;
    int BD = Bn * D;
    if (gid >= BD * C) return;
    int c  = gid / BD;
    int bd = gid - c * BD;
    int b  = bd / D;
    int d  = bd - b * D;

    float w = __expf(td[d]);
    float alpha = 0.f, beta = 0.f, eps = -1e30f;
    long base = ((long)b * T + (long)c * L) * D + d;

    const int P = 8;
    float kb0[P], vb0[P], kb1[P], vb1[P];

    auto step = [&](float kt, float vt) {
        float ww2  = eps - w;
        float tau2 = fmaxf(ww2, kt);
        float e1b  = __expf(ww2 - tau2);
        float e2b  = __expf(kt - tau2);
        alpha = e1b * alpha + e2b * vt;
        beta  = e1b * beta + e2b;
        eps   = tau2;
    };

#pragma unroll
    for (int j = 0; j < P; ++j) {
        long o = base + (long)j * D;
        kb0[j] = kk[o]; vb0[j] = (float)vv[o];
    }
    for (int t0 = 0; t0 < L; t0 += 2 * P) {
#pragma unroll
        for (int j = 0; j < P; ++j) {
            long o = base + (long)(t0 + P + j) * D;
            kb1[j] = kk[o]; vb1[j] = (float)vv[o];
        }
#pragma unroll
        for (int j = 0; j < P; ++j) step(kb0[j], vb0[j]);
        if (t0 + 2 * P < L) {
#pragma unroll
            for (int j = 0; j < P; ++j) {
                long o = base + (long)(t0 + 2 * P + j) * D;
                kb0[j] = kk[o]; vb0[j] = (float)vv[o];
            }
        }
#pragma unroll
        for (int j = 0; j < P; ++j) step(kb1[j], vb1[j]);
    }
    al[gid] = alpha; bl[gid] = beta; el[gid] = eps;
}

__global__ void wkv_combine(const float* __restrict__ al, const float* __restrict__ bl,
                            const float* __restrict__ el, const float* __restrict__ td,
                            float* __restrict__ ai, float* __restrict__ bi,
                            float* __restrict__ ei,
                            int Bn, int D, int C, int L) {
    int bd = blockIdx.x * blockDim.x + threadIdx.x;
    int BD = Bn * D;
    if (bd >= BD) return;
    int d = bd % D;
    float wL = __expf(td[d]) * (float)L;
    float a = 0.f, b2 = 0.f, e = -1e30f;
    for (int c = 0; c < C; ++c) {
        int idx = c * BD + bd;
        ai[idx] = a; bi[idx] = b2; ei[idx] = e;
        float ed  = e - wL;
        float la = al[idx], lb = bl[idx], le = el[idx];
        float tau = fmaxf(ed, le);
        float e1  = __expf(ed - tau);
        float e2  = __expf(le - tau);
        a  = a * e1 + la * e2;
        b2 = b2 * e1 + lb * e2;
        e  = tau;
    }
}

__global__ void wkv_pass2(const float* __restrict__ kk, const __bf16* __restrict__ vv,
                          const __bf16* __restrict__ rr,
                          const float* __restrict__ td, const float* __restrict__ tf,
                          const float* __restrict__ ai, const float* __restrict__ bi,
                          const float* __restrict__ ei,
                          __bf16* __restrict__ out,
                          int Bn, int T, int D, int C, int L) {
    int gid = blockIdx.x * blockDim.x + threadIdx.x;
    int BD = Bn * D;
    if (gid >= BD * C) return;
    int c  = gid / BD;
    int bd = gid - c * BD;
    int b  = bd / D;
    int d  = bd - b * D;

    float u = tf[d];
    float w = __expf(td[d]);
    float alpha = ai[gid], beta = bi[gid], eps = ei[gid];
    long base = ((long)b * T + (long)c * L) * D + d;

    const int P = 8;
    float kb0[P], vb0[P], rb0[P], kb1[P], vb1[P], rb1[P];

    auto step = [&](float kt, float vt, float rt, int tIdx) {
        float ww  = u + kt;
        float tau = fmaxf(eps, ww);
        float e1  = __expf(eps - tau);
        float e2  = __expf(ww - tau);
        float num = e1 * alpha + e2 * vt;
        float den = e1 * beta + e2;
        float o_  = num * __builtin_amdgcn_rcpf(den);
        float ww2  = eps - w;
        float tau2 = fmaxf(ww2, kt);
        float e1b  = __expf(ww2 - tau2);
        float e2b  = __expf(kt - tau2);
        alpha = e1b * alpha + e2b * vt;
        beta  = e1b * beta + e2b;
        eps   = tau2;
        float sr = __builtin_amdgcn_rcpf(1.0f + __expf(-rt));
        out[base + (long)tIdx * D] = (__bf16)(o_ * sr);
    };

#pragma unroll
    for (int j = 0; j < P; ++j) {
        long o = base + (long)j * D;
        kb0[j] = kk[o]; vb0[j] = (float)vv[o]; rb0[j] = (float)rr[o];
    }
    for (int t0 = 0; t0 < L; t0 += 2 * P) {
#pragma unroll
        for (int j = 0; j < P; ++j) {
            long o = base + (long)(t0 + P + j) * D;
            kb1[j] = kk[o]; vb1[j] = (float)vv[o]; rb1[j] = (float)rr[o];
        }
#pragma unroll
        for (int j = 0; j < P; ++j) step(kb0[j], vb0[j], rb0[j], t0 + j);
        if (t0 + 2 * P < L) {
#pragma unroll
            for (int j = 0; j < P; ++j) {
                long o = base + (long)(t0 + 2 * P + j) * D;
                kb0[j] = kk[o]; vb0[j] = (float)vv[o]; rb0[j] = (float)rr[o];
            }
        }
#pragma unroll
        for (int j = 0; j < P; ++j) step(kb1[j], vb1[j], rb1[j], t0 + P + j);
    }
}

// ---------------------------------------------------------------------------
extern "C" void kernel_launch(void* const* d_in, const int* in_sizes, int n_in,
                              void* d_out, int out_size, void* d_ws, size_t ws_size,
                              hipStream_t stream) {
    const float* x  = (const float*)d_in[0];
    const float* td = (const float*)d_in[1];
    const float* tf = (const float*)d_in[2];
    const float* mk = (const float*)d_in[3];
    const float* mv = (const float*)d_in[4];
    const float* mr = (const float*)d_in[5];
    const float* Wk = (const float*)d_in[6];
    const float* Wv = (const float*)d_in[7];
    const float* Wr = (const float*)d_in[8];
    const float* Wo = (const float*)d_in[9];
    float* out = (float*)d_out;

    const int D = in_sizes[1];                    // 2048
    const int T = 2048;
    const long total = (long)in_sizes[0];         // B*T*D
    const int Bn = (int)(total / ((long)T * D));  // 4
    const int M = Bn * T;
    const long DD = (long)D * D;
    const int C = 32;                             // scan chunks
    const int L = T / C;                          // 64
    const int BD = Bn * D;
    const int S = BD * C;

    // --- workspace layout (peak 192 MB; aliasing relies on stream order) ---
    char* p = (char*)d_ws;
    __bf16* xmk = (__bf16*)p;            p += total * 2;   // dead after gemm_k
    __bf16* xmv = (__bf16*)p;            p += total * 2;   // dead after gemm_bt2
    __bf16* xmr = (__bf16*)p;            p += total * 2;   // dead after gemm_bt2
    __bf16* wkb = (__bf16*)p;            p += DD * 2;      // dead after gemm_k
    __bf16* wvb = (__bf16*)p;            p += DD * 2;      // dead after gemm_bt2
    __bf16* wrb = (__bf16*)p;            p += DD * 2;      // dead after gemm_bt2
    __bf16* wob = (__bf16*)p;            p += DD * 2;      // live till end
    __bf16* vb  = (__bf16*)p;            p += total * 2;
    __bf16* rb  = (__bf16*)p;            p += total * 2;

    float*  kf = (float*)xmv;            // 64 MB over dead xmv+xmr
    __bf16* xo = xmk;                    // pass2 output over dead xmk
    float*  st = (float*)wkb;            // 6.3 MB scan state over dead wkb/wvb/wrb
    float *al = st, *bl = st + S, *el = st + 2 * S;
    float *ai = st + 3 * S, *bi = st + 4 * S, *ei = st + 5 * S;

    dim3 mixGrid((unsigned)((total / 8 + 255) / 256));
    dim3 cvtGrid((unsigned)((4 * DD / 8 + 255) / 256));
    dim3 gemmGrid(D / BN, M / BM);
    dim3 gemm2Grid(D / BN, M / BM, 2);
    dim3 p12Grid((S + 255) / 256);
    dim3 cmbGrid((BD + 255) / 256);

    cvt4_bf16<<<cvtGrid, 256, 0, stream>>>(Wk, Wv, Wr, Wo, wkb, wvb, wrb, wob, DD);
    mix3_kernel<<<mixGrid, 256, 0, stream>>>(x, mk, mv, mr, xmk, xmv, xmr, T, D, total);

    // v and r GEMMs first (they consume xmv/xmr, freeing the space kf reuses)
    gemm_bt2<<<gemm2Grid, 256, 0, stream>>>(xmv, xmr, wvb, wrb, vb, rb, M, D, D);
    gemm_bt<float><<<gemmGrid, 256, 0, stream>>>(xmk, wkb, kf, M, D, D);

    wkv_pass1<<<p12Grid, 256, 0, stream>>>(kf, vb, td, al, bl, el, Bn, T, D, C, L);
    wkv_combine<<<cmbGrid, 256, 0, stream>>>(al, bl, el, td, ai, bi, ei, Bn, D, C, L);
    wkv_pass2<<<p12Grid, 256, 0, stream>>>(kf, vb, rb, td, tf, ai, bi, ei, xo,
                                           Bn, T, D, C, L);

    gemm_bt<float><<<gemmGrid, 256, 0, stream>>>(xo, wob, out, M, D, D);
}

// Round 5
// 513.421 us; speedup vs baseline: 1.6646x; 1.0601x over previous
//
#include <hip/hip_runtime.h>
#include <stdint.h>

typedef __bf16 bf16x8 __attribute__((ext_vector_type(8)));
typedef float f32x4 __attribute__((ext_vector_type(4)));

#define BM 128
#define BN 128
#define BK 64

// ---------------------------------------------------------------------------
// Fused prep: (a) f32->bf16 convert of the 4 weight matrices, (b) time-shift
// mix producing all three mixed A-matrices (bf16). Block-uniform branch.
// ---------------------------------------------------------------------------
__global__ void prep_kernel(const float* __restrict__ w0, const float* __restrict__ w1,
                            const float* __restrict__ w2, const float* __restrict__ w3,
                            __bf16* __restrict__ o0, __bf16* __restrict__ o1,
                            __bf16* __restrict__ o2, __bf16* __restrict__ o3,
                            long DD, unsigned cvtBlocks,
                            const float* __restrict__ x,
                            const float* __restrict__ mk, const float* __restrict__ mv,
                            const float* __restrict__ mr,
                            __bf16* __restrict__ ok, __bf16* __restrict__ ov,
                            __bf16* __restrict__ orr,
                            int T, int D, long total) {
    if (blockIdx.x < cvtBlocks) {
        long idx = ((long)blockIdx.x * blockDim.x + threadIdx.x) * 8;
        if (idx >= 4 * DD) return;
        int w = (int)(idx / DD);            // block-uniform (DD % 2048 == 0)
        long off = idx - (long)w * DD;
        const float* in = (w == 0) ? w0 : (w == 1) ? w1 : (w == 2) ? w2 : w3;
        __bf16* out     = (w == 0) ? o0 : (w == 1) ? o1 : (w == 2) ? o2 : o3;
        f32x4 a = *(const f32x4*)(in + off);
        f32x4 b = *(const f32x4*)(in + off + 4);
        bf16x8 o;
#pragma unroll
        for (int i = 0; i < 4; ++i) { o[i] = (__bf16)a[i]; o[i + 4] = (__bf16)b[i]; }
        *(bf16x8*)(out + off) = o;
    } else {
        long idx = ((long)(blockIdx.x - cvtBlocks) * blockDim.x + threadIdx.x) * 8;
        if (idx >= total) return;
        int d = (int)(idx % D);
        long bt = idx / D;
        int t = (int)(bt % T);

        f32x4 x0 = *(const f32x4*)(x + idx);
        f32x4 x1 = *(const f32x4*)(x + idx + 4);
        f32x4 l0 = {}, l1 = {};
        if (t != 0) {
            l0 = *(const f32x4*)(x + idx - D);
            l1 = *(const f32x4*)(x + idx - D + 4);
        }
        const float* mw[3] = {mk, mv, mr};
        __bf16* ow[3] = {ok, ov, orr};
#pragma unroll
        for (int s = 0; s < 3; ++s) {
            f32x4 m0 = *(const f32x4*)(mw[s] + d);
            f32x4 m1 = *(const f32x4*)(mw[s] + d + 4);
            bf16x8 o;
#pragma unroll
            for (int i = 0; i < 4; ++i) {
                o[i]     = (__bf16)(x0[i] * m0[i] + l0[i] * (1.0f - m0[i]));
                o[i + 4] = (__bf16)(x1[i] * m1[i] + l1[i] * (1.0f - m1[i]));
            }
            *(bf16x8*)(ow[s] + idx) = o;
        }
    }
}

// ---------------------------------------------------------------------------
// GEMM body (m97-ladder structure, verified rounds 2-4).
// ---------------------------------------------------------------------------
template <typename CT>
__device__ __attribute__((always_inline))
void gemm_body(const __bf16* __restrict__ A, const __bf16* __restrict__ Bt,
               CT* __restrict__ C, int M, int N, int K) {
    __shared__ __align__(16) __bf16 sA[BM * BK];
    __shared__ __align__(16) __bf16 sB[BN * BK];

    const int tid  = threadIdx.x;
    const int lane = tid & 63;
    const int wave = tid >> 6;
    const int m0 = blockIdx.y * BM;
    const int n0 = blockIdx.x * BN;
    const int wm = (wave & 1) * 64;
    const int wn = (wave >> 1) * 64;

    const int l8 = lane >> 3;
    const int c8 = lane & 7;
    const int cg = c8 ^ l8;

    const int q  = lane >> 4;
    const int ml = lane & 15;

    f32x4 acc[4][4] = {};

    for (int k0 = 0; k0 < K; k0 += BK) {
#pragma unroll
        for (int i = 0; i < 4; ++i) {
            const int cl  = wave * 4 + i;
            const int row = cl * 8 + l8;
            const __bf16* gA = A  + (long)(m0 + row) * K + (k0 + cg * 8);
            const __bf16* gB = Bt + (long)(n0 + row) * K + (k0 + cg * 8);
            __builtin_amdgcn_global_load_lds(
                (const __attribute__((address_space(1))) void*)gA,
                (__attribute__((address_space(3))) void*)(sA + cl * 512), 16, 0, 0);
            __builtin_amdgcn_global_load_lds(
                (const __attribute__((address_space(1))) void*)gB,
                (__attribute__((address_space(3))) void*)(sB + cl * 512), 16, 0, 0);
        }
        __syncthreads();

#pragma unroll
        for (int kk = 0; kk < BK; kk += 32) {
            bf16x8 af[4], bfr[4];
#pragma unroll
            for (int i = 0; i < 4; ++i) {
                int row = wm + i * 16 + ml;
                int cl  = ((kk >> 3) + q) ^ (row & 7);
                af[i] = *(const bf16x8*)(sA + row * BK + cl * 8);
            }
#pragma unroll
            for (int j = 0; j < 4; ++j) {
                int row = wn + j * 16 + ml;
                int cl  = ((kk >> 3) + q) ^ (row & 7);
                bfr[j] = *(const bf16x8*)(sB + row * BK + cl * 8);
            }
#pragma unroll
            for (int i = 0; i < 4; ++i)
#pragma unroll
                for (int j = 0; j < 4; ++j)
                    acc[i][j] = __builtin_amdgcn_mfma_f32_16x16x32_bf16(
                        af[i], bfr[j], acc[i][j], 0, 0, 0);
        }
        __syncthreads();
    }

#pragma unroll
    for (int i = 0; i < 4; ++i)
#pragma unroll
        for (int j = 0; j < 4; ++j)
#pragma unroll
            for (int rg = 0; rg < 4; ++rg) {
                int row = m0 + wm + i * 16 + q * 4 + rg;
                int col = n0 + wn + j * 16 + ml;
                C[(long)row * N + col] = (CT)acc[i][j][rg];
            }
}

template <typename CT>
__global__ __launch_bounds__(256, 3)
void gemm_bt(const __bf16* __restrict__ A, const __bf16* __restrict__ Bt,
             CT* __restrict__ C, int M, int N, int K) {
    gemm_body<CT>(A, Bt, C, M, N, K);
}

// z-batched pair (v and r GEMMs), both bf16 outputs.
__global__ __launch_bounds__(256, 3)
void gemm_bt2(const __bf16* __restrict__ A0, const __bf16* __restrict__ A1,
              const __bf16* __restrict__ B0, const __bf16* __restrict__ B1,
              __bf16* __restrict__ C0, __bf16* __restrict__ C1,
              int M, int N, int K) {
    if (blockIdx.z == 0) gemm_body<__bf16>(A0, B0, C0, M, N, K);
    else                 gemm_body<__bf16>(A1, B1, C1, M, N, K);
}

// ---------------------------------------------------------------------------
// Chunk-parallel WKV scan (verified round 3). k f32, v/r bf16.
// pass1: per-chunk local (alpha,beta,eps).
// pass2: folds its own inbound state from (al,bl,el) in a block-uniform
//        <=C-1 step prologue (combine kernel fused away), then exact replay
//        with outputs + sigmoid(r) gate.
// ---------------------------------------------------------------------------
__global__ void wkv_pass1(const float* __restrict__ kk, const __bf16* __restrict__ vv,
                          const float* __restrict__ td,
                          float* __restrict__ al, float* __restrict__ bl,
                          float* __restrict__ el,
                          int Bn, int T, int D, int C, int L) {
    int gid = blockIdx.x * blockDim.x + threadIdx.x;
    int BD = Bn * D;
    if (gid >= BD * C) return;
    int c  = gid / BD;
    int bd = gid - c * BD;
    int b  = bd / D;
    int d  = bd - b * D;

    float w = __expf(td[d]);
    float alpha = 0.f, beta = 0.f, eps = -1e30f;
    long base = ((long)b * T + (long)c * L) * D + d;

    const int P = 8;
    float kb0[P], vb0[P], kb1[P], vb1[P];

    auto step = [&](float kt, float vt) {
        float ww2  = eps - w;
        float tau2 = fmaxf(ww2, kt);
        float e1b  = __expf(ww2 - tau2);
        float e2b  = __expf(kt - tau2);
        alpha = e1b * alpha + e2b * vt;
        beta  = e1b * beta + e2b;
        eps   = tau2;
    };

#pragma unroll
    for (int j = 0; j < P; ++j) {
        long o = base + (long)j * D;
        kb0[j] = kk[o]; vb0[j] = (float)vv[o];
    }
    for (int t0 = 0; t0 < L; t0 += 2 * P) {
#pragma unroll
        for (int j = 0; j < P; ++j) {
            long o = base + (long)(t0 + P + j) * D;
            kb1[j] = kk[o]; vb1[j] = (float)vv[o];
        }
#pragma unroll
        for (int j = 0; j < P; ++j) step(kb0[j], vb0[j]);
        if (t0 + 2 * P < L) {
#pragma unroll
            for (int j = 0; j < P; ++j) {
                long o = base + (long)(t0 + 2 * P + j) * D;
                kb0[j] = kk[o]; vb0[j] = (float)vv[o];
            }
        }
#pragma unroll
        for (int j = 0; j < P; ++j) step(kb1[j], vb1[j]);
    }
    al[gid] = alpha; bl[gid] = beta; el[gid] = eps;
}

__global__ void wkv_pass2(const float* __restrict__ kk, const __bf16* __restrict__ vv,
                          const __bf16* __restrict__ rr,
                          const float* __restrict__ td, const float* __restrict__ tf,
                          const float* __restrict__ al, const float* __restrict__ bl,
                          const float* __restrict__ el,
                          __bf16* __restrict__ out,
                          int Bn, int T, int D, int C, int L) {
    int gid = blockIdx.x * blockDim.x + threadIdx.x;
    int BD = Bn * D;
    if (gid >= BD * C) return;
    int c  = gid / BD;      // block-uniform (BD % 256 == 0)
    int bd = gid - c * BD;
    int b  = bd / D;
    int d  = bd - b * D;

    float u = tf[d];
    float w = __expf(td[d]);

    // --- fused combine: fold chunks 0..c-1 into this chunk's inbound state ---
    float alpha = 0.f, beta = 0.f, eps = -1e30f;
    {
        float wL = w * (float)L;
        for (int cc = 0; cc < c; ++cc) {
            int idx = cc * BD + bd;
            float ed  = eps - wL;
            float la = al[idx], lb = bl[idx], le = el[idx];
            float tau = fmaxf(ed, le);
            float e1  = __expf(ed - tau);
            float e2  = __expf(le - tau);
            alpha = alpha * e1 + la * e2;
            beta  = beta * e1 + lb * e2;
            eps   = tau;
        }
    }

    long base = ((long)b * T + (long)c * L) * D + d;

    const int P = 8;
    float kb0[P], vb0[P], rb0[P], kb1[P], vb1[P], rb1[P];

    auto step = [&](float kt, float vt, float rt, int tIdx) {
        float ww  = u + kt;
        float tau = fmaxf(eps, ww);
        float e1  = __expf(eps - tau);
        float e2  = __expf(ww - tau);
        float num = e1 * alpha + e2 * vt;
        float den = e1 * beta + e2;
        float o_  = num * __builtin_amdgcn_rcpf(den);
        float ww2  = eps - w;
        float tau2 = fmaxf(ww2, kt);
        float e1b  = __expf(ww2 - tau2);
        float e2b  = __expf(kt - tau2);
        alpha = e1b * alpha + e2b * vt;
        beta  = e1b * beta + e2b;
        eps   = tau2;
        float sr = __builtin_amdgcn_rcpf(1.0f + __expf(-rt));
        out[base + (long)tIdx * D] = (__bf16)(o_ * sr);
    };

#pragma unroll
    for (int j = 0; j < P; ++j) {
        long o = base + (long)j * D;
        kb0[j] = kk[o]; vb0[j] = (float)vv[o]; rb0[j] = (float)rr[o];
    }
    for (int t0 = 0; t0 < L; t0 += 2 * P) {
#pragma unroll
        for (int j = 0; j < P; ++j) {
            long o = base + (long)(t0 + P + j) * D;
            kb1[j] = kk[o]; vb1[j] = (float)vv[o]; rb1[j] = (float)rr[o];
        }
#pragma unroll
        for (int j = 0; j < P; ++j) step(kb0[j], vb0[j], rb0[j], t0 + j);
        if (t0 + 2 * P < L) {
#pragma unroll
            for (int j = 0; j < P; ++j) {
                long o = base + (long)(t0 + 2 * P + j) * D;
                kb0[j] = kk[o]; vb0[j] = (float)vv[o]; rb0[j] = (float)rr[o];
            }
        }
#pragma unroll
        for (int j = 0; j < P; ++j) step(kb1[j], vb1[j], rb1[j], t0 + P + j);
    }
}

// ---------------------------------------------------------------------------
extern "C" void kernel_launch(void* const* d_in, const int* in_sizes, int n_in,
                              void* d_out, int out_size, void* d_ws, size_t ws_size,
                              hipStream_t stream) {
    const float* x  = (const float*)d_in[0];
    const float* td = (const float*)d_in[1];
    const float* tf = (const float*)d_in[2];
    const float* mk = (const float*)d_in[3];
    const float* mv = (const float*)d_in[4];
    const float* mr = (const float*)d_in[5];
    const float* Wk = (const float*)d_in[6];
    const float* Wv = (const float*)d_in[7];
    const float* Wr = (const float*)d_in[8];
    const float* Wo = (const float*)d_in[9];
    float* out = (float*)d_out;

    const int D = in_sizes[1];                    // 2048
    const int T = 2048;
    const long total = (long)in_sizes[0];         // B*T*D
    const int Bn = (int)(total / ((long)T * D));  // 4
    const int M = Bn * T;
    const long DD = (long)D * D;
    const int C = 32;                             // scan chunks
    const int L = T / C;                          // 64
    const int BD = Bn * D;
    const int S = BD * C;

    // --- workspace layout (peak 192 MB; aliasing relies on stream order) ---
    char* p = (char*)d_ws;
    __bf16* xmk = (__bf16*)p;            p += total * 2;   // dead after gemm_k
    __bf16* xmv = (__bf16*)p;            p += total * 2;   // dead after gemm_bt2
    __bf16* xmr = (__bf16*)p;            p += total * 2;   // dead after gemm_bt2
    __bf16* wkb = (__bf16*)p;            p += DD * 2;      // dead after gemm_k
    __bf16* wvb = (__bf16*)p;            p += DD * 2;      // dead after gemm_bt2
    __bf16* wrb = (__bf16*)p;            p += DD * 2;      // dead after gemm_bt2
    __bf16* wob = (__bf16*)p;            p += DD * 2;      // live till end
    __bf16* vb  = (__bf16*)p;            p += total * 2;
    __bf16* rb  = (__bf16*)p;            p += total * 2;

    float*  kf = (float*)xmv;            // 64 MB over dead xmv+xmr
    __bf16* xo = xmk;                    // pass2 output over dead xmk
    float*  st = (float*)wkb;            // 3.1 MB scan state over dead wkb
    float *al = st, *bl = st + S, *el = st + 2 * S;

    unsigned cvtBlocks = (unsigned)((4 * DD / 8 + 255) / 256);
    unsigned mixBlocks = (unsigned)((total / 8 + 255) / 256);
    dim3 prepGrid(cvtBlocks + mixBlocks);
    dim3 gemmGrid(D / BN, M / BM);
    dim3 gemm2Grid(D / BN, M / BM, 2);
    dim3 p12Grid((S + 255) / 256);

    prep_kernel<<<prepGrid, 256, 0, stream>>>(Wk, Wv, Wr, Wo, wkb, wvb, wrb, wob,
                                              DD, cvtBlocks,
                                              x, mk, mv, mr, xmk, xmv, xmr,
                                              T, D, total);

    // v and r GEMMs first (they consume xmv/xmr, freeing the space kf reuses)
    gemm_bt2<<<gemm2Grid, 256, 0, stream>>>(xmv, xmr, wvb, wrb, vb, rb, M, D, D);
    gemm_bt<float><<<gemmGrid, 256, 0, stream>>>(xmk, wkb, kf, M, D, D);

    wkv_pass1<<<p12Grid, 256, 0, stream>>>(kf, vb, td, al, bl, el, Bn, T, D, C, L);
    wkv_pass2<<<p12Grid, 256, 0, stream>>>(kf, vb, rb, td, tf, al, bl, el, xo,
                                           Bn, T, D, C, L);

    gemm_bt<float><<<gemmGrid, 256, 0, stream>>>(xo, wob, out, M, D, D);
}